// Round 7
// baseline (200.588 us; speedup 1.0000x reference)
//
#include <hip/hip_runtime.h>

// ANI loss: per-voxel 3x3 symmetric eigen (closed form), masked L1 reduction.
// input_data [4,6,96,96,96] f32, target [4,6,96,96,96] f32, mask [4,1,96,96,96] i32,
// gt_mean [6] f32, gt_std [6] f32  ->  scalar f32 loss.
//
// R7: one voxel per thread. R4/R6 showed VGPR_Count=32 < the 52 regs needed
// for 13 float4 loads in flight -> compiler chunks the batch into 2-3 loads
// + serial waitcnt -> ~5 serial memory round trips/thread (67us, VALU 20%,
// HBM 17%). launch_bounds and sched_barrier both failed to stop it. With one
// voxel/thread the batch is 13 dword loads = 13 VGPRs: no pressure, all 13
// issue together, one round trip. Coalescing unchanged (lane i -> base+i).

namespace {
constexpr int SB    = 96 * 96 * 96;   // voxels per volume = 884736
constexpr int BATCH = 4;
constexpr int NVOX  = SB * BATCH;     // 3538944
constexpr int BLOCK = 256;
constexpr int GRID  = NVOX / BLOCK;   // 13824 blocks (exact)
constexpr int BLOCK2 = 1024;

// Returns p*cos(acos(r)/3); q via out-param. Branchless, NaN-free.
__device__ __forceinline__ float eig_pc(const float y0, const float y1, const float y2,
                                        const float y3, const float y4, const float y5,
                                        float& q_out) {
    const float q  = (y0 + y3 + y5) * (1.0f / 3.0f);
    const float d0 = y0 - q, d1 = y3 - q, d2 = y5 - q;
    float p2 = d0 * d0;
    p2 = fmaf(d1, d1, p2);
    p2 = fmaf(d2, d2, p2);
    float c2 = y1 * y1;
    c2 = fmaf(y2, y2, c2);
    c2 = fmaf(y4, y4, c2);
    p2 = fmaf(2.0f, c2, p2);
    const float p2s = p2 * (1.0f / 6.0f);
    const float inv = rsqrtf(fmaxf(p2s, 1e-12f));  // 1/p (guarded)
    const float p   = p2s * inv;                   // = sqrt(p2s); ~0 when guarded

    // det(A - qI), unnormalized
    const float m0 = fmaf(d1, d2, -(y4 * y4));
    const float m1 = fmaf(y1, d2, -(y4 * y2));
    const float m2 = fmaf(y1, y4, -(d1 * y2));
    float det = d0 * m0;
    det = fmaf(-y1, m1, det);
    det = fmaf( y2, m2, det);

    float r = 0.5f * det * (inv * inv * inv);
    r = fminf(fmaxf(r, -1.0f + 1e-7f), 1.0f - 1e-7f);

    // acos(r) = r>=0 ?  sqrt(1-r)*P(r)  :  pi - sqrt(1+r)*P(-r)   (A&S 4.4.45)
    const float a  = fabsf(r);
    const float sq = sqrtf(1.0f - a);
    float poly = fmaf(a, -0.0187293f, 0.0742610f);
    poly = fmaf(a, poly, -0.2121144f);
    poly = fmaf(a, poly, 1.5707288f);
    const float t  = sq * poly;
    const float th = (r < 0.0f) ? (3.14159265358979f - t) : t;
    const float phi = th * (1.0f / 3.0f);

    // cos(phi), phi in [0, pi/3]
    const float u = phi * phi;
    float c = fmaf(u, 2.4801587e-5f, -1.3888889e-3f);
    c = fmaf(u, c, 4.16666679e-2f);
    c = fmaf(u, c, -0.5f);
    c = fmaf(u, c, 1.0f);

    q_out = q;
    return p * c;
}

__global__ __launch_bounds__(BLOCK) void ani_reduce(
    const float* __restrict__ in, const float* __restrict__ tg,
    const int*  __restrict__ mask,
    const float* __restrict__ gt_mean, const float* __restrict__ gt_std,
    float* __restrict__ ws) {

    const int i  = blockIdx.x * BLOCK + threadIdx.x;   // one voxel
    const int b  = i / SB;
    const int s  = i - b * SB;
    const int base = (b * 6) * SB + s;

    // ---- load batch: 13 independent dword loads, all in flight together ----
    float vi[6], vt[6];
#pragma unroll
    for (int c = 0; c < 6; ++c) {
        vi[c] = in[base + c * SB];
        vt[c] = tg[base + c * SB];
    }
    const float mf = (float)mask[b * SB + s];

    float st[6], mn[6];
#pragma unroll
    for (int c = 0; c < 6; ++c) { st[c] = gt_std[c]; mn[c] = gt_mean[c]; }

    float yi[6], yt[6];
#pragma unroll
    for (int c = 0; c < 6; ++c) {
        yi[c] = fmaf(vi[c], st[c], mn[c]);   // mask NOT applied (zero-weight voxels
        yt[c] = fmaf(vt[c], st[c], mn[c]);   // contribute nothing; math is NaN-free)
    }
    float qi, qt;
    float pci = eig_pc(yi[0], yi[1], yi[2], yi[3], yi[4], yi[5], qi);
    float pct = eig_pc(yt[0], yt[1], yt[2], yt[3], yt[4], yt[5], qt);
    float ani_in = 3.0f * pci;          // i2 - 0.5*(i0+i1)
    float ani_tg = qt - pct;            // 0.5*(t0+t1)
    float sum_abs = fabsf(ani_in - ani_tg) * mf;
    float sum_m   = mf;

    // wave-64 reduction
#pragma unroll
    for (int off = 32; off > 0; off >>= 1) {
        sum_abs += __shfl_down(sum_abs, off, 64);
        sum_m   += __shfl_down(sum_m,   off, 64);
    }
    __shared__ float s_abs[BLOCK / 64];
    __shared__ float s_m[BLOCK / 64];
    int lane = threadIdx.x & 63;
    int wid  = threadIdx.x >> 6;
    if (lane == 0) { s_abs[wid] = sum_abs; s_m[wid] = sum_m; }
    __syncthreads();
    if (threadIdx.x == 0) {
        float ta = 0.0f, tm = 0.0f;
#pragma unroll
        for (int w = 0; w < BLOCK / 64; ++w) { ta += s_abs[w]; tm += s_m[w]; }
        // Uncontended per-block partial stores (no atomics).
        ws[blockIdx.x]        = ta;
        ws[GRID + blockIdx.x] = tm;
    }
}

__global__ __launch_bounds__(BLOCK2) void ani_stage2(
    const float* __restrict__ ws, float* __restrict__ out) {
    float sa = 0.0f, sm = 0.0f;
    for (int i = threadIdx.x; i < GRID; i += BLOCK2) {
        sa += ws[i];
        sm += ws[GRID + i];
    }
#pragma unroll
    for (int off = 32; off > 0; off >>= 1) {
        sa += __shfl_down(sa, off, 64);
        sm += __shfl_down(sm, off, 64);
    }
    __shared__ float s_abs[BLOCK2 / 64];
    __shared__ float s_m[BLOCK2 / 64];
    int lane = threadIdx.x & 63;
    int wid  = threadIdx.x >> 6;
    if (lane == 0) { s_abs[wid] = sa; s_m[wid] = sm; }
    __syncthreads();
    if (threadIdx.x == 0) {
        float ta = 0.0f, tm = 0.0f;
#pragma unroll
        for (int w = 0; w < BLOCK2 / 64; ++w) { ta += s_abs[w]; tm += s_m[w]; }
        out[0] = ta / fmaxf(tm, 1.0f);
    }
}

} // namespace

extern "C" void kernel_launch(void* const* d_in, const int* in_sizes, int n_in,
                              void* d_out, int out_size, void* d_ws, size_t ws_size,
                              hipStream_t stream) {
    const float* in      = (const float*)d_in[0];
    const float* tg      = (const float*)d_in[1];
    const int*   mask    = (const int*)d_in[2];
    const float* gt_mean = (const float*)d_in[3];
    const float* gt_std  = (const float*)d_in[4];
    float* ws  = (float*)d_ws;   // needs 2*GRID floats = 110.6 KB
    float* out = (float*)d_out;

    ani_reduce<<<GRID, BLOCK, 0, stream>>>(in, tg, mask, gt_mean, gt_std, ws);
    ani_stage2<<<1, BLOCK2, 0, stream>>>(ws, out);
}

// Round 8
// 197.940 us; speedup vs baseline: 1.0134x; 1.0134x over previous
//
#include <hip/hip_runtime.h>

// ANI loss: per-voxel 3x3 symmetric eigen (closed form), masked L1 reduction.
// input_data [4,6,96,96,96] f32, target [4,6,96,96,96] f32, mask [4,1,96,96,96] i32,
// gt_mean [6] f32, gt_std [6] f32  ->  scalar f32 loss.
//
// R8: async global->LDS staging. R4-R7 all pinned ~65us with both pipes idle:
// the register allocator refuses to keep a 13-load batch live in VGPRs
// (VGPR_Count 12-64 across attempts) -> 4-6 serial memory round trips per
// thread. global_load_lds is fire-and-forget DMA (zero VGPR in flight, the
// compiler CANNOT chunk it): each wave issues 13 global_load_lds_dwordx4
// (16B/lane) for its private 256-voxel x 13-channel tile, one vmcnt(0), then
// computes 4 voxels/thread from LDS (ds_read_b128, short latency). No
// __syncthreads for staging: wave reads only its own LDS segment.
// LDS 53KB/block -> 3 blocks/CU; in-flight/CU = 12 waves x 13.3KB ~ 160KB.

namespace {
constexpr int SB    = 96 * 96 * 96;   // voxels per volume = 884736
constexpr int BATCH = 4;
constexpr int NVOX  = SB * BATCH;     // 3538944
constexpr int BLOCK = 256;            // 4 waves
constexpr int TILE  = 1024;           // voxels per block (4 per thread)
constexpr int BPB   = SB / TILE;      // 864 blocks per batch (exact)
constexpr int GRID  = NVOX / TILE;    // 3456 blocks (exact)
constexpr int BLOCK2 = 1024;

__device__ __forceinline__ void async16(const void* g, void* l) {
    // per-lane global gather -> LDS at (wave-uniform l) + lane*16B
    __builtin_amdgcn_global_load_lds(
        (const __attribute__((address_space(1))) void*)g,
        (__attribute__((address_space(3))) void*)l,
        16, 0, 0);
}

__device__ __forceinline__ float f4get(const float4& v, int j) {
    return ((const float*)&v)[j];
}

// Returns p*cos(acos(r)/3); q via out-param. Branchless, NaN-free.
__device__ __forceinline__ float eig_pc(const float y0, const float y1, const float y2,
                                        const float y3, const float y4, const float y5,
                                        float& q_out) {
    const float q  = (y0 + y3 + y5) * (1.0f / 3.0f);
    const float d0 = y0 - q, d1 = y3 - q, d2 = y5 - q;
    float p2 = d0 * d0;
    p2 = fmaf(d1, d1, p2);
    p2 = fmaf(d2, d2, p2);
    float c2 = y1 * y1;
    c2 = fmaf(y2, y2, c2);
    c2 = fmaf(y4, y4, c2);
    p2 = fmaf(2.0f, c2, p2);
    const float p2s = p2 * (1.0f / 6.0f);
    const float inv = rsqrtf(fmaxf(p2s, 1e-12f));  // 1/p (guarded)
    const float p   = p2s * inv;                   // = sqrt(p2s); ~0 when guarded

    // det(A - qI), unnormalized
    const float m0 = fmaf(d1, d2, -(y4 * y4));
    const float m1 = fmaf(y1, d2, -(y4 * y2));
    const float m2 = fmaf(y1, y4, -(d1 * y2));
    float det = d0 * m0;
    det = fmaf(-y1, m1, det);
    det = fmaf( y2, m2, det);

    float r = 0.5f * det * (inv * inv * inv);
    r = fminf(fmaxf(r, -1.0f + 1e-7f), 1.0f - 1e-7f);

    // acos(r) = r>=0 ?  sqrt(1-r)*P(r)  :  pi - sqrt(1+r)*P(-r)   (A&S 4.4.45)
    const float a  = fabsf(r);
    const float sq = sqrtf(1.0f - a);
    float poly = fmaf(a, -0.0187293f, 0.0742610f);
    poly = fmaf(a, poly, -0.2121144f);
    poly = fmaf(a, poly, 1.5707288f);
    const float t  = sq * poly;
    const float th = (r < 0.0f) ? (3.14159265358979f - t) : t;
    const float phi = th * (1.0f / 3.0f);

    // cos(phi), phi in [0, pi/3]
    const float u = phi * phi;
    float c = fmaf(u, 2.4801587e-5f, -1.3888889e-3f);
    c = fmaf(u, c, 4.16666679e-2f);
    c = fmaf(u, c, -0.5f);
    c = fmaf(u, c, 1.0f);

    q_out = q;
    return p * c;
}

__global__ __launch_bounds__(BLOCK) void ani_reduce(
    const float* __restrict__ in, const float* __restrict__ tg,
    const int*  __restrict__ mask,
    const float* __restrict__ gt_mean, const float* __restrict__ gt_std,
    float* __restrict__ ws) {

    __shared__ float ldsf[12 * TILE];   // [c][voxel]: c 0..5 = input, 6..11 = target
    __shared__ int   ldsm[TILE];        // mask

    const int tid  = threadIdx.x;
    const int w    = tid >> 6;          // wave id (uniform per wave)
    const int lane = tid & 63;
    const int l4   = lane * 4;

    const int bb   = blockIdx.x / BPB;              // batch index
    const int tile = (blockIdx.x - bb * BPB) * TILE;
    const int cb   = bb * 6 * SB + tile;            // + c*SB per channel
    const int wv   = w * 256;                       // wave's voxel offset in tile

    // ---- 13 fire-and-forget DMA loads per wave (zero VGPR in flight) ----
#pragma unroll
    for (int c = 0; c < 6; ++c)
        async16(in + cb + c * SB + wv + l4, &ldsf[c * TILE + wv]);
#pragma unroll
    for (int c = 0; c < 6; ++c)
        async16(tg + cb + c * SB + wv + l4, &ldsf[(6 + c) * TILE + wv]);
    async16(mask + bb * SB + tile + wv + l4, &ldsm[wv]);

    asm volatile("s_waitcnt vmcnt(0)" ::: "memory");
    // No barrier: this wave reads only the LDS it staged itself.

    float st[6], mn[6];
#pragma unroll
    for (int c = 0; c < 6; ++c) { st[c] = gt_std[c]; mn[c] = gt_mean[c]; }

    float sum_abs = 0.0f;
    float sum_m   = 0.0f;

    // thread's 4 voxels: tile-local [wv + 4*lane, wv + 4*lane + 4)
    float4 xi[6], xt[6];
#pragma unroll
    for (int c = 0; c < 6; ++c) {
        xi[c] = *(const float4*)&ldsf[c * TILE + wv + l4];
        xt[c] = *(const float4*)&ldsf[(6 + c) * TILE + wv + l4];
    }
    int4 mk = *(const int4*)&ldsm[wv + l4];
    int mks[4] = {mk.x, mk.y, mk.z, mk.w};

#pragma unroll
    for (int j = 0; j < 4; ++j) {
        float mf = (float)mks[j];
        float yi[6], yt[6];
#pragma unroll
        for (int c = 0; c < 6; ++c) {
            yi[c] = fmaf(f4get(xi[c], j), st[c], mn[c]);   // mask NOT applied
            yt[c] = fmaf(f4get(xt[c], j), st[c], mn[c]);
        }
        float qi, qt;
        float pci = eig_pc(yi[0], yi[1], yi[2], yi[3], yi[4], yi[5], qi);
        float pct = eig_pc(yt[0], yt[1], yt[2], yt[3], yt[4], yt[5], qt);
        float ani_in = 3.0f * pci;          // i2 - 0.5*(i0+i1)
        float ani_tg = qt - pct;            // 0.5*(t0+t1)
        sum_abs = fmaf(fabsf(ani_in - ani_tg), mf, sum_abs);
        sum_m  += mf;
    }

    // wave-64 reduction
#pragma unroll
    for (int off = 32; off > 0; off >>= 1) {
        sum_abs += __shfl_down(sum_abs, off, 64);
        sum_m   += __shfl_down(sum_m,   off, 64);
    }
    __shared__ float s_abs[BLOCK / 64];
    __shared__ float s_m[BLOCK / 64];
    if (lane == 0) { s_abs[w] = sum_abs; s_m[w] = sum_m; }
    __syncthreads();
    if (tid == 0) {
        float ta = 0.0f, tm = 0.0f;
#pragma unroll
        for (int v = 0; v < BLOCK / 64; ++v) { ta += s_abs[v]; tm += s_m[v]; }
        // Uncontended per-block partial stores (no atomics).
        ws[blockIdx.x]        = ta;
        ws[GRID + blockIdx.x] = tm;
    }
}

__global__ __launch_bounds__(BLOCK2) void ani_stage2(
    const float* __restrict__ ws, float* __restrict__ out) {
    float sa = 0.0f, sm = 0.0f;
    for (int i = threadIdx.x; i < GRID; i += BLOCK2) {
        sa += ws[i];
        sm += ws[GRID + i];
    }
#pragma unroll
    for (int off = 32; off > 0; off >>= 1) {
        sa += __shfl_down(sa, off, 64);
        sm += __shfl_down(sm, off, 64);
    }
    __shared__ float s_abs[BLOCK2 / 64];
    __shared__ float s_m[BLOCK2 / 64];
    int lane = threadIdx.x & 63;
    int wid  = threadIdx.x >> 6;
    if (lane == 0) { s_abs[wid] = sa; s_m[wid] = sm; }
    __syncthreads();
    if (threadIdx.x == 0) {
        float ta = 0.0f, tm = 0.0f;
#pragma unroll
        for (int w = 0; w < BLOCK2 / 64; ++w) { ta += s_abs[w]; tm += s_m[w]; }
        out[0] = ta / fmaxf(tm, 1.0f);
    }
}

} // namespace

extern "C" void kernel_launch(void* const* d_in, const int* in_sizes, int n_in,
                              void* d_out, int out_size, void* d_ws, size_t ws_size,
                              hipStream_t stream) {
    const float* in      = (const float*)d_in[0];
    const float* tg      = (const float*)d_in[1];
    const int*   mask    = (const int*)d_in[2];
    const float* gt_mean = (const float*)d_in[3];
    const float* gt_std  = (const float*)d_in[4];
    float* ws  = (float*)d_ws;   // needs 2*GRID floats = 27.6 KB
    float* out = (float*)d_out;

    ani_reduce<<<GRID, BLOCK, 0, stream>>>(in, tg, mask, gt_mean, gt_std, ws);
    ani_stage2<<<1, BLOCK2, 0, stream>>>(ws, out);
}

// Round 9
// 184.224 us; speedup vs baseline: 1.0888x; 1.0745x over previous
//
#include <hip/hip_runtime.h>

// ANI loss: per-voxel 3x3 symmetric eigen (closed form), masked L1 reduction.
// input_data [4,6,96,96,96] f32, target [4,6,96,96,96] f32, mask [4,1,96,96,96] i32,
// gt_mean [6] f32, gt_std [6] f32  ->  scalar f32 loss.
//
// R9: non-temporal loads. Evidence so far: duration pinned at ~65-67us across
// VGPR-batch (R4-R7) and LDS-DMA (R8) structures; R8 raised per-CU outstanding
// bytes 28x with 0% gain; cache-resident replays (hbm_gbps~3) also take 67us.
// => not latency/MLP-bound, not DRAM-bound: an on-chip ~2.75 TB/s read-rate
// cap. Theory: L2-allocation/fill path (~128 B/cyc/XCD). Data is touched
// once — bypass allocation with __builtin_nontemporal_load (nt bit) on all
// 13 streams. Structure otherwise identical to R7 (1 voxel/thread, best
// occupancy). If neutral: pattern read ceiling reached (~87% of m13's
// implied 3.15 TB/s read component).

namespace {
constexpr int SB    = 96 * 96 * 96;   // voxels per volume = 884736
constexpr int BATCH = 4;
constexpr int NVOX  = SB * BATCH;     // 3538944
constexpr int BLOCK = 256;
constexpr int GRID  = NVOX / BLOCK;   // 13824 blocks (exact)
constexpr int BLOCK2 = 1024;

// Returns p*cos(acos(r)/3); q via out-param. Branchless, NaN-free.
__device__ __forceinline__ float eig_pc(const float y0, const float y1, const float y2,
                                        const float y3, const float y4, const float y5,
                                        float& q_out) {
    const float q  = (y0 + y3 + y5) * (1.0f / 3.0f);
    const float d0 = y0 - q, d1 = y3 - q, d2 = y5 - q;
    float p2 = d0 * d0;
    p2 = fmaf(d1, d1, p2);
    p2 = fmaf(d2, d2, p2);
    float c2 = y1 * y1;
    c2 = fmaf(y2, y2, c2);
    c2 = fmaf(y4, y4, c2);
    p2 = fmaf(2.0f, c2, p2);
    const float p2s = p2 * (1.0f / 6.0f);
    const float inv = rsqrtf(fmaxf(p2s, 1e-12f));  // 1/p (guarded)
    const float p   = p2s * inv;                   // = sqrt(p2s); ~0 when guarded

    // det(A - qI), unnormalized
    const float m0 = fmaf(d1, d2, -(y4 * y4));
    const float m1 = fmaf(y1, d2, -(y4 * y2));
    const float m2 = fmaf(y1, y4, -(d1 * y2));
    float det = d0 * m0;
    det = fmaf(-y1, m1, det);
    det = fmaf( y2, m2, det);

    float r = 0.5f * det * (inv * inv * inv);
    r = fminf(fmaxf(r, -1.0f + 1e-7f), 1.0f - 1e-7f);

    // acos(r) = r>=0 ?  sqrt(1-r)*P(r)  :  pi - sqrt(1+r)*P(-r)   (A&S 4.4.45)
    const float a  = fabsf(r);
    const float sq = sqrtf(1.0f - a);
    float poly = fmaf(a, -0.0187293f, 0.0742610f);
    poly = fmaf(a, poly, -0.2121144f);
    poly = fmaf(a, poly, 1.5707288f);
    const float t  = sq * poly;
    const float th = (r < 0.0f) ? (3.14159265358979f - t) : t;
    const float phi = th * (1.0f / 3.0f);

    // cos(phi), phi in [0, pi/3]
    const float u = phi * phi;
    float c = fmaf(u, 2.4801587e-5f, -1.3888889e-3f);
    c = fmaf(u, c, 4.16666679e-2f);
    c = fmaf(u, c, -0.5f);
    c = fmaf(u, c, 1.0f);

    q_out = q;
    return p * c;
}

__global__ __launch_bounds__(BLOCK) void ani_reduce(
    const float* __restrict__ in, const float* __restrict__ tg,
    const int*  __restrict__ mask,
    const float* __restrict__ gt_mean, const float* __restrict__ gt_std,
    float* __restrict__ ws) {

    const int i  = blockIdx.x * BLOCK + threadIdx.x;   // one voxel
    const int b  = i / SB;
    const int s  = i - b * SB;
    const int base = (b * 6) * SB + s;

    // ---- 13 independent non-temporal dword loads (nt: no L2 allocation) ----
    float vi[6], vt[6];
#pragma unroll
    for (int c = 0; c < 6; ++c) {
        vi[c] = __builtin_nontemporal_load(in + base + c * SB);
        vt[c] = __builtin_nontemporal_load(tg + base + c * SB);
    }
    const float mf = (float)__builtin_nontemporal_load(mask + b * SB + s);

    float st[6], mn[6];
#pragma unroll
    for (int c = 0; c < 6; ++c) { st[c] = gt_std[c]; mn[c] = gt_mean[c]; }

    float yi[6], yt[6];
#pragma unroll
    for (int c = 0; c < 6; ++c) {
        yi[c] = fmaf(vi[c], st[c], mn[c]);   // mask NOT applied (zero-weight voxels
        yt[c] = fmaf(vt[c], st[c], mn[c]);   // contribute nothing; math is NaN-free)
    }
    float qi, qt;
    float pci = eig_pc(yi[0], yi[1], yi[2], yi[3], yi[4], yi[5], qi);
    float pct = eig_pc(yt[0], yt[1], yt[2], yt[3], yt[4], yt[5], qt);
    float ani_in = 3.0f * pci;          // i2 - 0.5*(i0+i1)
    float ani_tg = qt - pct;            // 0.5*(t0+t1)
    float sum_abs = fabsf(ani_in - ani_tg) * mf;
    float sum_m   = mf;

    // wave-64 reduction
#pragma unroll
    for (int off = 32; off > 0; off >>= 1) {
        sum_abs += __shfl_down(sum_abs, off, 64);
        sum_m   += __shfl_down(sum_m,   off, 64);
    }
    __shared__ float s_abs[BLOCK / 64];
    __shared__ float s_m[BLOCK / 64];
    int lane = threadIdx.x & 63;
    int wid  = threadIdx.x >> 6;
    if (lane == 0) { s_abs[wid] = sum_abs; s_m[wid] = sum_m; }
    __syncthreads();
    if (threadIdx.x == 0) {
        float ta = 0.0f, tm = 0.0f;
#pragma unroll
        for (int w = 0; w < BLOCK / 64; ++w) { ta += s_abs[w]; tm += s_m[w]; }
        // Uncontended per-block partial stores (no atomics).
        ws[blockIdx.x]        = ta;
        ws[GRID + blockIdx.x] = tm;
    }
}

__global__ __launch_bounds__(BLOCK2) void ani_stage2(
    const float* __restrict__ ws, float* __restrict__ out) {
    float sa = 0.0f, sm = 0.0f;
    for (int i = threadIdx.x; i < GRID; i += BLOCK2) {
        sa += ws[i];
        sm += ws[GRID + i];
    }
#pragma unroll
    for (int off = 32; off > 0; off >>= 1) {
        sa += __shfl_down(sa, off, 64);
        sm += __shfl_down(sm, off, 64);
    }
    __shared__ float s_abs[BLOCK2 / 64];
    __shared__ float s_m[BLOCK2 / 64];
    int lane = threadIdx.x & 63;
    int wid  = threadIdx.x >> 6;
    if (lane == 0) { s_abs[wid] = sa; s_m[wid] = sm; }
    __syncthreads();
    if (threadIdx.x == 0) {
        float ta = 0.0f, tm = 0.0f;
#pragma unroll
        for (int w = 0; w < BLOCK2 / 64; ++w) { ta += s_abs[w]; tm += s_m[w]; }
        out[0] = ta / fmaxf(tm, 1.0f);
    }
}

} // namespace

extern "C" void kernel_launch(void* const* d_in, const int* in_sizes, int n_in,
                              void* d_out, int out_size, void* d_ws, size_t ws_size,
                              hipStream_t stream) {
    const float* in      = (const float*)d_in[0];
    const float* tg      = (const float*)d_in[1];
    const int*   mask    = (const int*)d_in[2];
    const float* gt_mean = (const float*)d_in[3];
    const float* gt_std  = (const float*)d_in[4];
    float* ws  = (float*)d_ws;   // needs 2*GRID floats = 110.6 KB
    float* out = (float*)d_out;

    ani_reduce<<<GRID, BLOCK, 0, stream>>>(in, tg, mask, gt_mean, gt_std, ws);
    ani_stage2<<<1, BLOCK2, 0, stream>>>(ws, out);
}